// Round 1
// baseline (279.282 us; speedup 1.0000x reference)
//
#include <hip/hip_runtime.h>

#define LEVELS 256
#define NROWS 64
#define ROWLEN 786432            // elements per row
#define CHUNKS 24                // chunks per row; 786432/24 = 32768 elems/chunk
#define CHUNK_ELEMS (ROWLEN / CHUNKS)
#define BLOCK 256
#define WAVES (BLOCK / 64)

__global__ __launch_bounds__(256) void zero_ws_kernel(unsigned int* __restrict__ ws) {
    int i = blockIdx.x * blockDim.x + threadIdx.x;
    if (i < NROWS * LEVELS) ws[i] = 0u;
}

__global__ __launch_bounds__(256) void hist_kernel(const int* __restrict__ x,
                                                   unsigned int* __restrict__ ws) {
    __shared__ unsigned int lhist[WAVES][LEVELS];   // per-wave private histograms (4 KiB)

    const int row   = blockIdx.y;
    const int chunk = blockIdx.x;
    const int tid   = threadIdx.x;
    const int wave  = tid >> 6;

    // zero LDS histograms
    unsigned int* flat = &lhist[0][0];
    for (int i = tid; i < WAVES * LEVELS; i += BLOCK) flat[i] = 0u;
    __syncthreads();

    // int4 vectorized grid-stride over this block's chunk
    const int4* xr = (const int4*)(x + (long)row * ROWLEN + (long)chunk * CHUNK_ELEMS);
    const int n4 = CHUNK_ELEMS / 4;          // 8192 int4 per block, 32 per thread
    for (int i = tid; i < n4; i += BLOCK) {
        int4 v = xr[i];
        atomicAdd(&lhist[wave][v.x & 255], 1u);
        atomicAdd(&lhist[wave][v.y & 255], 1u);
        atomicAdd(&lhist[wave][v.z & 255], 1u);
        atomicAdd(&lhist[wave][v.w & 255], 1u);
    }
    __syncthreads();

    // reduce waves and flush one atomic per bin
    for (int b = tid; b < LEVELS; b += BLOCK) {
        unsigned int s = 0u;
        #pragma unroll
        for (int w = 0; w < WAVES; ++w) s += lhist[w][b];
        if (s) atomicAdd(&ws[row * LEVELS + b], s);
    }
}

__global__ __launch_bounds__(256) void broadcast_kernel(const unsigned int* __restrict__ ws,
                                                        float* __restrict__ out) {
    // out[b][v][c] = (float)ws[b*256+v]; each thread writes one float4.
    // Total float4s: 64*256*256/4 = 1,048,576 -> 4096 blocks of 256.
    long i  = (long)blockIdx.x * BLOCK + threadIdx.x;
    long bv = i >> 6;                       // 64 float4 stores per (b, v)
    float val = (float)ws[bv];
    ((float4*)out)[i] = make_float4(val, val, val, val);
}

extern "C" void kernel_launch(void* const* d_in, const int* in_sizes, int n_in,
                              void* d_out, int out_size, void* d_ws, size_t ws_size,
                              hipStream_t stream) {
    const int* x = (const int*)d_in[0];
    float* out = (float*)d_out;
    unsigned int* ws = (unsigned int*)d_ws;   // 64*256 uint32 = 64 KiB accumulator

    // 1) zero the accumulator (d_ws is poisoned to 0xAA before every call)
    zero_ws_kernel<<<(NROWS * LEVELS + BLOCK - 1) / BLOCK, BLOCK, 0, stream>>>(ws);

    // 2) per-row histograms
    dim3 grid(CHUNKS, NROWS);
    hist_kernel<<<grid, BLOCK, 0, stream>>>(x, ws);

    // 3) broadcast hist[b][v] across the 256-wide last dim, as float
    long total4 = (long)NROWS * LEVELS * LEVELS / 4;
    broadcast_kernel<<<(int)(total4 / BLOCK), BLOCK, 0, stream>>>(ws, out);
}

// Round 2
// 279.194 us; speedup vs baseline: 1.0003x; 1.0003x over previous
//
#include <hip/hip_runtime.h>

#define LEVELS 256
#define NROWS 64
#define ROWLEN 786432            // elements per row
#define CHUNKS 32                // 2048 blocks x 4 waves = 8192 waves = full occupancy
#define CHUNK_ELEMS (ROWLEN / CHUNKS)   // 24576
#define BLOCK 256
#define WAVES (BLOCK / 64)

__global__ __launch_bounds__(256) void zero_ws_kernel(unsigned int* __restrict__ ws) {
    int i = blockIdx.x * blockDim.x + threadIdx.x;
    if (i < NROWS * LEVELS) ws[i] = 0u;
}

__global__ __launch_bounds__(256) void hist_kernel(const int* __restrict__ x,
                                                   unsigned int* __restrict__ ws) {
    __shared__ unsigned int lhist[WAVES][LEVELS];   // per-wave private histograms (4 KiB)

    const int row   = blockIdx.y;
    const int chunk = blockIdx.x;
    const int tid   = threadIdx.x;
    const int wave  = tid >> 6;

    // zero LDS histograms
    unsigned int* flat = &lhist[0][0];
    for (int i = tid; i < WAVES * LEVELS; i += BLOCK) flat[i] = 0u;
    __syncthreads();

    // two independent int4 loads per iteration for MLP; both issued before atomics
    const int4* xr = (const int4*)(x + (long)row * ROWLEN + (long)chunk * CHUNK_ELEMS);
    const int n4 = CHUNK_ELEMS / 4;          // 6144 int4 per block; 12 iters of 2
    unsigned int* h = lhist[wave];
    for (int i = tid; i < n4; i += 2 * BLOCK) {
        int4 a = xr[i];
        int4 b = xr[i + BLOCK];
        atomicAdd(&h[a.x & 255], 1u);
        atomicAdd(&h[a.y & 255], 1u);
        atomicAdd(&h[a.z & 255], 1u);
        atomicAdd(&h[a.w & 255], 1u);
        atomicAdd(&h[b.x & 255], 1u);
        atomicAdd(&h[b.y & 255], 1u);
        atomicAdd(&h[b.z & 255], 1u);
        atomicAdd(&h[b.w & 255], 1u);
    }
    __syncthreads();

    // reduce waves and flush one global atomic per bin per block
    for (int bin = tid; bin < LEVELS; bin += BLOCK) {
        unsigned int s = 0u;
        #pragma unroll
        for (int w = 0; w < WAVES; ++w) s += lhist[w][bin];
        if (s) atomicAdd(&ws[row * LEVELS + bin], s);
    }
}

__global__ __launch_bounds__(256) void broadcast_kernel(const unsigned int* __restrict__ ws,
                                                        float* __restrict__ out) {
    // out[b][v][c] = (float)ws[b*256+v]; each thread writes one float4.
    long i  = (long)blockIdx.x * BLOCK + threadIdx.x;
    long bv = i >> 6;                       // 64 float4 stores per (b, v)
    float val = (float)ws[bv];
    ((float4*)out)[i] = make_float4(val, val, val, val);
}

extern "C" void kernel_launch(void* const* d_in, const int* in_sizes, int n_in,
                              void* d_out, int out_size, void* d_ws, size_t ws_size,
                              hipStream_t stream) {
    const int* x = (const int*)d_in[0];
    float* out = (float*)d_out;
    unsigned int* ws = (unsigned int*)d_ws;   // 64*256 uint32 = 64 KiB accumulator

    // 1) zero the accumulator (d_ws is poisoned to 0xAA before every call)
    zero_ws_kernel<<<(NROWS * LEVELS + BLOCK - 1) / BLOCK, BLOCK, 0, stream>>>(ws);

    // 2) per-row histograms
    dim3 grid(CHUNKS, NROWS);
    hist_kernel<<<grid, BLOCK, 0, stream>>>(x, ws);

    // 3) broadcast hist[b][v] across the 256-wide last dim, as float
    long total4 = (long)NROWS * LEVELS * LEVELS / 4;
    broadcast_kernel<<<(int)(total4 / BLOCK), BLOCK, 0, stream>>>(ws, out);
}

// Round 3
// 278.596 us; speedup vs baseline: 1.0025x; 1.0021x over previous
//
#include <hip/hip_runtime.h>

#define LEVELS 256
#define NROWS 64
#define ROWLEN 786432                    // elements per row
#define CHUNKS 32                        // 2048 blocks x 4 waves = full occupancy
#define CHUNK_ELEMS (ROWLEN / CHUNKS)    // 24576
#define BLOCK 256
#define WAVES (BLOCK / 64)

// Kernel 1: per-(row,chunk) partial histograms, written with PLAIN stores
// (no global atomics, no pre-zeroing needed — every slot fully written).
// ws layout: partial[row*CHUNKS + chunk][256] u32  -> 2048*256*4 = 2 MB.
__global__ __launch_bounds__(256) void hist_partial_kernel(const int* __restrict__ x,
                                                           unsigned int* __restrict__ ws) {
    __shared__ unsigned int lhist[WAVES][LEVELS];   // per-wave private histograms (4 KiB)

    const int row   = blockIdx.y;
    const int chunk = blockIdx.x;
    const int tid   = threadIdx.x;
    const int wave  = tid >> 6;

    unsigned int* flat = &lhist[0][0];
    for (int i = tid; i < WAVES * LEVELS; i += BLOCK) flat[i] = 0u;
    __syncthreads();

    const int4* xr = (const int4*)(x + (long)row * ROWLEN + (long)chunk * CHUNK_ELEMS);
    const int n4 = CHUNK_ELEMS / 4;                 // 6144 int4 per block
    unsigned int* h = lhist[wave];
    for (int i = tid; i < n4; i += 2 * BLOCK) {
        int4 a = xr[i];
        int4 b = xr[i + BLOCK];
        atomicAdd(&h[a.x & 255], 1u);
        atomicAdd(&h[a.y & 255], 1u);
        atomicAdd(&h[a.z & 255], 1u);
        atomicAdd(&h[a.w & 255], 1u);
        atomicAdd(&h[b.x & 255], 1u);
        atomicAdd(&h[b.y & 255], 1u);
        atomicAdd(&h[b.z & 255], 1u);
        atomicAdd(&h[b.w & 255], 1u);
    }
    __syncthreads();

    // reduce 4 waves -> 256 partial bins, plain coalesced stores
    unsigned int* dst = ws + ((long)(row * CHUNKS + chunk)) * LEVELS;
    for (int bin = tid; bin < LEVELS; bin += BLOCK) {
        unsigned int s = 0u;
        #pragma unroll
        for (int w = 0; w < WAVES; ++w) s += lhist[w][bin];
        dst[bin] = s;                                // plain store
    }
}

// Kernel 2: reduce the 32 chunk-partials per (row,bin) and broadcast across
// the 256-wide last dim. One block handles (row, 4 bins); one wave per bin.
__global__ __launch_bounds__(256) void reduce_broadcast_kernel(const unsigned int* __restrict__ ws,
                                                               float* __restrict__ out) {
    const int b    = blockIdx.x >> 6;          // row  (grid = 64 rows * 64 bin-groups)
    const int vg   = blockIdx.x & 63;          // bin group of 4
    const int wave = threadIdx.x >> 6;
    const int lane = threadIdx.x & 63;
    const int bin  = vg * 4 + wave;

    // each chunk's partial loaded by two lanes (lane&31); butterfly over 32
    unsigned int v = ws[((long)(b * CHUNKS) + (lane & 31)) * LEVELS + bin];
    #pragma unroll
    for (int m = 1; m <= 16; m <<= 1) v += (unsigned int)__shfl_xor((int)v, m);
    float val = (float)v;                      // full sum over 32 chunks, all lanes

    // out[b][bin][0..255] : 64 float4 stores, one per lane
    float4* dst = (float4*)(out + ((long)b * LEVELS + bin) * LEVELS);
    dst[lane] = make_float4(val, val, val, val);
}

extern "C" void kernel_launch(void* const* d_in, const int* in_sizes, int n_in,
                              void* d_out, int out_size, void* d_ws, size_t ws_size,
                              hipStream_t stream) {
    const int* x = (const int*)d_in[0];
    float* out = (float*)d_out;
    unsigned int* ws = (unsigned int*)d_ws;    // 2 MB of partials, fully overwritten

    dim3 grid(CHUNKS, NROWS);
    hist_partial_kernel<<<grid, BLOCK, 0, stream>>>(x, ws);

    reduce_broadcast_kernel<<<NROWS * 64, BLOCK, 0, stream>>>(ws, out);
}